// Round 1
// baseline (177.258 us; speedup 1.0000x reference)
//
#include <hip/hip_runtime.h>
#include <hip/hip_fp16.h>

// Volume: [B=2, X=128, Y=128, Z=128, C=1] fp32, grid: [B, N=2^21, 3] in [0,1].
// Output: [B, N, 1] fp32 trilinear samples.
// image flat index = b*2^21 + x*2^14 + y*2^7 + z  (z fastest).
//
// R2: fp16 volume in d_ws -> FETCH 594->127 MB, 180->132 us.
// R3: z-pair gathers (4 divergent loads/sample) + XCD batch-parity swizzle.
// R4: corner-cube record layout. rocprof on R3 shows the sampler at 18% HBM,
//     8.8% VALU, 74% occ -> bound by divergent-gather request rate:
//     16.8M line-requests (4/sample) x 64B = 1.07 GB of random L2 traffic in
//     90 us = ~12 TB/s, the random-64B L2 ceiling. Fix = request count, not
//     hit rate: prepass builds a 16B record per voxel holding ALL 8 trilinear
//     corners as four half2 z-pairs -> ONE aligned 16B gather per sample
//     (4x fewer line-requests, 1 dependent load instead of 4). Grid/out
//     streams use nontemporal so they don't evict record lines from L2.

#define TOTAL   (2 * 2097152)   // B * N samples
#define LOG2N   21              // N = 2^21 per batch; VOL = 2^21 voxels too
#define VOL     (128 * 128 * 128)
#define NVOX    (2 * VOL)

// ---- R4 pre-pass: fp32 volume -> 16B corner-cube records in workspace ----
// rec[b,x,y,z] = { h2(c[x,y,z],   c[x,y,z+1]),      // q11 z-pair
//                  h2(c[x+1,y,z], c[x+1,y,z+1]),    // q21
//                  h2(c[x,y+1,z], c[x,y+1,z+1]),    // q12
//                  h2(c[x+1,y+1,z], c[x+1,y+1,z+1]) } // q22
// (+1 clamped at 127; records at x==127 / y==127 are never read by the
//  sampler since clip() keeps floor() <= 126, but we fill them anyway.)
__global__ __launch_bounds__(256)
void ImageWarped_build_rec_kernel(const float* __restrict__ in,
                                  uint4* __restrict__ rec)
{
    const int idx = blockIdx.x * 256 + threadIdx.x;  // 0..NVOX-1, z fastest
    const int v   = idx & (VOL - 1);
    const int x   = v >> 14;
    const int y   = (v >> 7) & 127;
    const int z   = v & 127;
    const int zp  = min(z + 1, 127);
    const int xo  = (x < 127) ? (1 << 14) : 0;
    const int yo  = (y < 127) ? (1 << 7)  : 0;

    // row base (x,y) of this thread's batch: in + b*2^21 + x*2^14 + y*2^7
    const float* __restrict__ r11 = in + (idx - z);
    const float* __restrict__ r21 = r11 + xo;
    const float* __restrict__ r12 = r11 + yo;
    const float* __restrict__ r22 = r21 + yo;

    union { __half2 h; unsigned u; } p0, p1, p2, p3;
    p0.h = __floats2half2_rn(r11[z], r11[zp]);
    p1.h = __floats2half2_rn(r21[z], r21[zp]);
    p2.h = __floats2half2_rn(r12[z], r12[zp]);
    p3.h = __floats2half2_rn(r22[z], r22[zp]);

    rec[idx] = make_uint4(p0.u, p1.u, p2.u, p3.u);   // 16B coalesced store
}

// ---- R4 main: trilinear sample, ONE 16B record gather per sample ---------
__global__ __launch_bounds__(256)
void ImageWarped_trilinear_rec_kernel(const uint4* __restrict__ rec,
                                      const float* __restrict__ grid,
                                      float* __restrict__ out)
{
    // Batch-parity swizzle: round-robin blockIdx%8 -> XCD means each XCD's
    // L2 only sees ONE batch's 33.5 MB record set.
    const int batch = blockIdx.x & 1;
    const int s     = (blockIdx.x >> 1) * 256 + threadIdx.x;  // within batch
    const int i     = (batch << LOG2N) | s;                   // global sample

    // Non-temporal: pure stream, read once -> keep out of L2.
    const float gx = __builtin_nontemporal_load(grid + 3 * i + 0);
    const float gy = __builtin_nontemporal_load(grid + 3 * i + 1);
    const float gz = __builtin_nontemporal_load(grid + 3 * i + 2);

    // idx = clip(grid * 128, 0.001, 126.999)
    const float xf = fminf(fmaxf(gx * 128.0f, 0.001f), 126.999f);
    const float yf = fminf(fmaxf(gy * 128.0f, 0.001f), 126.999f);
    const float zf = fminf(fmaxf(gz * 128.0f, 0.001f), 126.999f);

    const float x1f = floorf(xf), x2f = ceilf(xf);
    const float y1f = floorf(yf), y2f = ceilf(yf);
    const float z1f = floorf(zf), z2f = ceilf(zf);

    // Literal two-weight form: if a coord is integral both weights are 0
    // (reference semantics), NOT w/1-w.
    const float wx  = xf - x1f, wx2 = x2f - xf;
    const float wy  = yf - y1f, wy2 = y2f - yf;
    const float wz  = zf - z1f, wz2 = z2f - zf;

    const int ix1 = (int)x1f;
    const int iy1 = (int)y1f;
    const int iz1 = (int)z1f;

    // One 16B-aligned gather holding all 8 corners.
    const int base = (batch << LOG2N) + (ix1 << 14) + (iy1 << 7) + iz1;
    const uint4 u = rec[base];

    auto zlerp = [&](unsigned w) -> float {
        union { unsigned u32; __half2 h; } c;
        c.u32 = w;                               // (c_z1, c_z2)
        const float2 f = __half22float2(c.h);
        return f.x * wz2 + f.y * wz;             // literal form
    };
    const float q11 = zlerp(u.x);
    const float q21 = zlerp(u.y);
    const float q12 = zlerp(u.z);
    const float q22 = zlerp(u.w);

    // multilinear expansion == reference up to FP reassociation
    const float r = (q21 * wx + q11 * wx2) * wy2
                  + (q22 * wx + q12 * wx2) * wy;
    __builtin_nontemporal_store(r, out + i);
}

// ---- R3 pre-pass (fallback): fp32 volume -> fp16 volume ------------------
__global__ __launch_bounds__(256)
void ImageWarped_cvt_fp16_kernel(const float* __restrict__ in,
                                 __half* __restrict__ out)
{
    const int i = blockIdx.x * 256 + threadIdx.x;   // NVOX/4 threads
    const float4 v = ((const float4*)in)[i];
    union { __half2 h2[2]; uint2 u; } p;
    p.h2[0] = __floats2half2_rn(v.x, v.y);
    p.h2[1] = __floats2half2_rn(v.z, v.w);
    ((uint2*)out)[i] = p.u;
}

// ---- R3 main (fallback): trilinear gather, z-pairs via 8B windows --------
__global__ __launch_bounds__(256)
void ImageWarped_trilinear_h2_kernel(const __half* __restrict__ image,
                                     const float* __restrict__ grid,
                                     float* __restrict__ out)
{
    const int batch = blockIdx.x & 1;
    const int s     = (blockIdx.x >> 1) * 256 + threadIdx.x;
    const int i     = (batch << LOG2N) | s;

    const float gx = grid[3 * i + 0];
    const float gy = grid[3 * i + 1];
    const float gz = grid[3 * i + 2];

    const __half* __restrict__ img = image + ((size_t)batch << LOG2N);

    const float xf = fminf(fmaxf(gx * 128.0f, 0.001f), 126.999f);
    const float yf = fminf(fmaxf(gy * 128.0f, 0.001f), 126.999f);
    const float zf = fminf(fmaxf(gz * 128.0f, 0.001f), 126.999f);

    const float x1f = floorf(xf), x2f = ceilf(xf);
    const float y1f = floorf(yf), y2f = ceilf(yf);
    const float z1f = floorf(zf), z2f = ceilf(zf);

    const float wx  = xf - x1f, wx2 = x2f - xf;
    const float wy  = yf - y1f, wy2 = y2f - yf;
    const float wz  = zf - z1f, wz2 = z2f - zf;

    const int ix1 = (int)x1f, ix2 = (int)x2f;
    const int iy1 = (int)y1f, iy2 = (int)y2f;
    const int iz1 = (int)z1f;

    const int bx1 = ix1 << 14, bx2 = ix2 << 14;
    const int by1 = iy1 << 7,  by2 = iy2 << 7;

    const int ze = min(iz1 & ~1, 124);
    const int sh = (iz1 - ze) << 4;

    const float  ww  = wz2, wwz = wz;
    auto zfetch = [&](int off) -> float {
        const uint2 u = *(const uint2*)(img + off + ze);
        unsigned long long w = ((unsigned long long)u.y << 32) | u.x;
        w >>= sh;
        union { unsigned int u32; __half2 h; } c;
        c.u32 = (unsigned int)w;
        const float2 f = __half22float2(c.h);
        return f.x * ww + f.y * wwz;
    };

    const float q11 = zfetch(bx1 + by1);
    const float q21 = zfetch(bx2 + by1);
    const float q12 = zfetch(bx1 + by2);
    const float q22 = zfetch(bx2 + by2);

    out[i] = (q21 * wx + q11 * wx2) * wy2
           + (q22 * wx + q12 * wx2) * wy;
}

// ---- fallback (R1 kernel, fp32 gathers) if ws too small ------------------
__global__ __launch_bounds__(256)
void ImageWarped_trilinear_f_kernel(const float* __restrict__ image,
                                    const float* __restrict__ grid,
                                    float* __restrict__ out)
{
    const int i = blockIdx.x * 256 + threadIdx.x;
    if (i >= TOTAL) return;

    const float gx = grid[3 * i + 0];
    const float gy = grid[3 * i + 1];
    const float gz = grid[3 * i + 2];

    const int b = i >> LOG2N;
    const float* __restrict__ img = image + (size_t)b * VOL;

    const float xf = fminf(fmaxf(gx * 128.0f, 0.001f), 126.999f);
    const float yf = fminf(fmaxf(gy * 128.0f, 0.001f), 126.999f);
    const float zf = fminf(fmaxf(gz * 128.0f, 0.001f), 126.999f);

    const float x1f = floorf(xf), x2f = ceilf(xf);
    const float y1f = floorf(yf), y2f = ceilf(yf);
    const float z1f = floorf(zf), z2f = ceilf(zf);

    const float wx  = xf - x1f, wx2 = x2f - xf;
    const float wy  = yf - y1f, wy2 = y2f - yf;
    const float wz  = zf - z1f, wz2 = z2f - zf;

    const int ix1 = (int)x1f, ix2 = (int)x2f;
    const int iy1 = (int)y1f, iy2 = (int)y2f;
    const int iz1 = (int)z1f, iz2 = (int)z2f;

    const int bx1 = ix1 << 14, bx2 = ix2 << 14;
    const int by1 = iy1 << 7,  by2 = iy2 << 7;

    const float c111 = img[bx1 + by1 + iz1];
    const float c211 = img[bx2 + by1 + iz1];
    const float c121 = img[bx1 + by2 + iz1];
    const float c221 = img[bx2 + by2 + iz1];
    const float c112 = img[bx1 + by1 + iz2];
    const float c212 = img[bx2 + by1 + iz2];
    const float c122 = img[bx1 + by2 + iz2];
    const float c222 = img[bx2 + by2 + iz2];

    const float lerp_y1 = (c211 * wx + c111 * wx2) * wy2
                        + (c221 * wx + c121 * wx2) * wy;
    const float lerp_y2 = (c212 * wx + c112 * wx2) * wy2
                        + (c222 * wx + c122 * wx2) * wy;

    out[i] = lerp_y2 * wz + lerp_y1 * wz2;
}

extern "C" void kernel_launch(void* const* d_in, const int* in_sizes, int n_in,
                              void* d_out, int out_size, void* d_ws, size_t ws_size,
                              hipStream_t stream)
{
    const float* image = (const float*)d_in[0];  // [2,128,128,128,1] fp32
    const float* grid  = (const float*)d_in[1];  // [2,2097152,3]     fp32
    float* out = (float*)d_out;                  // [2,2097152,1]     fp32

    const int blocks = (TOTAL + 255) / 256;      // 16384

    if (ws_size >= (size_t)NVOX * sizeof(uint4)) {          // 67.1 MB
        uint4* rec = (uint4*)d_ws;
        ImageWarped_build_rec_kernel<<<NVOX / 256, 256, 0, stream>>>(image, rec);
        ImageWarped_trilinear_rec_kernel<<<blocks, 256, 0, stream>>>(rec, grid, out);
    } else if (ws_size >= (size_t)NVOX * sizeof(__half)) {  // 8.4 MB
        __half* img16 = (__half*)d_ws;
        ImageWarped_cvt_fp16_kernel<<<NVOX / 4 / 256, 256, 0, stream>>>(image, img16);
        ImageWarped_trilinear_h2_kernel<<<blocks, 256, 0, stream>>>(img16, grid, out);
    } else {
        ImageWarped_trilinear_f_kernel<<<blocks, 256, 0, stream>>>(image, grid, out);
    }
}